// Round 1
// baseline (625.829 us; speedup 1.0000x reference)
//
#include <hip/hip_runtime.h>
#include <math.h>

// CRF layer: B=2048 sequences, T=512 max steps, C=32 tags.
// out = [ tags as float (B*T) | loss (1) ], total 1048577 floats.
#define BB 2048
#define TT 512
#define CC 32

__global__ void zero_loss_kernel(float* __restrict__ out) {
  if (threadIdx.x == 0) out[(size_t)BB * TT] = 0.0f;
}

// One wave (64 lanes) per batch element.
// lane = h*32 + c : c = current tag [0,32), h = which half of the prev-tag
// range this lane reduces over (h=0 -> p in [0,16), h=1 -> p in [16,32)).
// Both halves carry bitwise-identical copies of alpha (all combining ops are
// commutative-exact fp32), so width-32 shuffles serve both halves.
__global__ __launch_bounds__(256) void crf_kernel(
    const float* __restrict__ logits,     // [B, T, C]
    const int*   __restrict__ seqlen,     // [B]
    const int*   __restrict__ labels,     // [B, T]
    const float* __restrict__ trans,      // [C, C]  trans[p*C + c]
    float*       __restrict__ out)        // [B*T + 1]
{
  // backpointers for t = 1..511 stored at row t-1. 4*511*32 = 65,408 B.
  __shared__ unsigned char bp_s[4][TT - 1][CC];

  const int w    = threadIdx.x >> 6;
  const int lane = threadIdx.x & 63;
  const int c    = lane & 31;
  const int h    = lane >> 5;
  const int b    = blockIdx.x * 4 + w;

  const int len = seqlen[b];
  const float* lg  = logits + (size_t)b * TT * CC;
  const int*   lab = labels + (size_t)b * TT;
  const size_t bT  = (size_t)b * TT;

  // Preload my 16 transition entries: tr[i] = trans[(h*16+i)][c]
  float tr[16];
#pragma unroll
  for (int i = 0; i < 16; ++i) tr[i] = trans[(h * 16 + i) * CC + c];

  // ---------- gold-path score (unary + binary), lane-parallel over t ----------
  float uacc = 0.0f, bacc = 0.0f;
#pragma unroll
  for (int j = 0; j < 8; ++j) {
    int t = lane + 64 * j;            // t < 512 always; guard by len
    if (t < len) {
      int lt = lab[t];
      uacc += lg[t * CC + lt];        // unary: t = 0..len-1
      if (t + 1 < len) {              // binary pairs: t = 0..len-2
        int ln = lab[t + 1];
        bacc += trans[lt * CC + ln];
      }
    }
  }
#pragma unroll
  for (int d = 32; d >= 1; d >>= 1) {
    uacc += __shfl_xor(uacc, d);
    bacc += __shfl_xor(bacc, d);
  }

  // ---------- fused Viterbi + forward recursion over t = 1..len-1 ----------
  float av = lg[c];   // viterbi score for tag c
  float af = av;      // forward  (log-alpha) for tag c

  for (int t = 1; t < len; ++t) {
    float logit_c = lg[t * CC + c];   // issued early; consumed at step end

    float best = -INFINITY;
    int   bpi  = 0;
    float fmax = -INFINITY;
    float sf[16];
#pragma unroll
    for (int i = 0; i < 16; ++i) {
      const int p = h * 16 + i;
      float pav = __shfl(av, p, 32);
      float paf = __shfl(af, p, 32);
      float sv = pav + tr[i];
      float s2 = paf + tr[i];
      if (sv > best) { best = sv; bpi = p; }   // strict > keeps first index
      fmax = fmaxf(fmax, s2);
      sf[i] = s2;
    }

    // combine the two halves for viterbi; tie prefers lower p (half 0)
    {
      float ov = __shfl_xor(best, 32);
      int   oi = __shfl_xor(bpi, 32);
      float Av = h ? ov   : best;   int Ai = h ? oi  : bpi;
      float Bv = h ? best : ov;     int Bi = h ? bpi : oi;
      bool tB = Bv > Av;
      best = tB ? Bv : Av;
      bpi  = tB ? Bi : Ai;
    }

    // forward: logsumexp over all 32 prev tags
    float om = __shfl_xor(fmax, 32);
    float m  = fmaxf(fmax, om);
    float s  = 0.0f;
#pragma unroll
    for (int i = 0; i < 16; ++i) s += __expf(sf[i] - m);
    s += __shfl_xor(s, 32);

    av = logit_c + best;
    af = logit_c + (m + __logf(s));

    if (h == 0) bp_s[w][t - 1][c] = (unsigned char)bpi;
  }

  // ---------- last tag: argmax over c (first index on ties) ----------
  float v = av; int idx = c;
#pragma unroll
  for (int d = 1; d < 32; d <<= 1) {
    float v2 = __shfl_xor(v, d, 32);
    int   i2 = __shfl_xor(idx, d, 32);
    if (v2 > v || (v2 == v && i2 < idx)) { v = v2; idx = i2; }
  }

  // ---------- log partition ----------
  float mm = af;
#pragma unroll
  for (int d = 1; d < 32; d <<= 1) mm = fmaxf(mm, __shfl_xor(mm, d, 32));
  float ss = __expf(af - mm);
#pragma unroll
  for (int d = 1; d < 32; d <<= 1) ss += __shfl_xor(ss, d, 32);
  float log_norm = mm + __logf(ss);

  // ---------- backtrace + outputs ----------
  if (lane == 0) {
    int tag = idx;
    for (int t = len - 1; t > 0; --t) {
      out[bT + t] = (float)tag;
      tag = bp_s[w][t - 1][tag];
    }
    out[bT] = (float)tag;

    float ll = uacc + bacc - log_norm;
    atomicAdd(out + (size_t)BB * TT, -ll * (1.0f / BB));
  }
  // zero-fill padded positions t >= len
  for (int t = len + lane; t < TT; t += 64) out[bT + t] = 0.0f;
}

extern "C" void kernel_launch(void* const* d_in, const int* in_sizes, int n_in,
                              void* d_out, int out_size, void* d_ws, size_t ws_size,
                              hipStream_t stream) {
  const float* logits = (const float*)d_in[0];
  const int*   seqlen = (const int*)d_in[1];
  const int*   labels = (const int*)d_in[2];
  const float* trans  = (const float*)d_in[3];
  float* out = (float*)d_out;

  zero_loss_kernel<<<1, 64, 0, stream>>>(out);
  crf_kernel<<<dim3(BB / 4), dim3(256), 0, stream>>>(logits, seqlen, labels, trans, out);
}

// Round 2
// 554.570 us; speedup vs baseline: 1.1285x; 1.1285x over previous
//
#include <hip/hip_runtime.h>
#include <math.h>

// CRF layer: B=2048 sequences, T=512 max steps, C=32 tags.
// out = [ tags as float (B*T) | loss (1) ], total 1048577 floats.
#define BB 2048
#define TT 512
#define CC 32

__global__ void zero_loss_kernel(float* __restrict__ out) {
  if (threadIdx.x == 0) out[(size_t)BB * TT] = 0.0f;
}

// One wave (64 lanes) per batch element, one wave per block.
// lane = h*32 + c : c = current tag, h selects which 16 prev-tags this lane
// reduces over. Alpha vectors are exchanged through LDS (ds_read_b128 x8)
// instead of 32 bpermutes; logits are register-prefetched 2 steps ahead.
__global__ __launch_bounds__(64, 2) void crf_kernel(
    const float* __restrict__ logits,     // [B, T, C]
    const int*   __restrict__ seqlen,     // [B]
    const int*   __restrict__ labels,     // [B, T]
    const float* __restrict__ trans,      // [C, C]  trans[p*C + c]
    float*       __restrict__ out)        // [B*T + 1]
{
  __shared__ unsigned char bp_s[(TT - 1) * CC];       // 16,352 B backpointers
  __shared__ __align__(16) float avs[CC];             // viterbi alpha
  __shared__ __align__(16) float afs[CC];             // forward alpha

  const int lane = threadIdx.x;          // 0..63
  const int c    = lane & 31;
  const int h    = lane >> 5;
  const int b    = blockIdx.x;

  const int len = seqlen[b];
  const float* lg  = logits + (size_t)b * TT * CC;
  const int*   lab = labels + (size_t)b * TT;
  const size_t bT  = (size_t)b * TT;

  // my 16 transition entries: tr[i] = trans[(h*16+i)][c]
  float tr[16];
#pragma unroll
  for (int i = 0; i < 16; ++i) tr[i] = trans[(h * 16 + i) * CC + c];

  // ---------- init t = 0 ----------
  float av = lg[c];
  float af = av;
  if (h == 0) { avs[c] = av; afs[c] = af; }
  __syncthreads();

  // logits register pipeline, 2 steps deep, clamped to last valid row
  const int lastrow = (len - 1) * CC;
  int r1 = CC     > lastrow ? lastrow : CC;
  int r2 = 2 * CC > lastrow ? lastrow : 2 * CC;
  float l0 = lg[r1 + c];
  float l1 = lg[r2 + c];

  // ---------- fused Viterbi + forward recursion ----------
  for (int t = 1; t < len; ++t) {
    float logit_c = l0;
    l0 = l1;
    int rn = (t + 2) * CC;
    l1 = lg[(rn > lastrow ? lastrow : rn) + c];

    // fetch my half's 16 av + 16 af from LDS (4+4 ds_read_b128)
    float pav[16], paf[16];
    const float4* avp = (const float4*)(avs + h * 16);
    const float4* afp = (const float4*)(afs + h * 16);
#pragma unroll
    for (int q = 0; q < 4; ++q) ((float4*)pav)[q] = avp[q];
#pragma unroll
    for (int q = 0; q < 4; ++q) ((float4*)paf)[q] = afp[q];

    float sv[16]; int si[16]; float sf[16];
#pragma unroll
    for (int i = 0; i < 16; ++i) {
      sv[i] = pav[i] + tr[i];
      sf[i] = paf[i] + tr[i];
      si[i] = h * 16 + i;
    }

    // viterbi argmax tree (first index wins ties: strict >)
#pragma unroll
    for (int w = 8; w >= 1; w >>= 1) {
#pragma unroll
      for (int k = 0; k < 8; ++k) {
        if (k < w) {
          if (sv[k + w] > sv[k]) { sv[k] = sv[k + w]; si[k] = si[k + w]; }
        }
      }
    }
    float best = sv[0];
    int   bpi  = si[0];

    // max tree for logsumexp
    float m8[8];
#pragma unroll
    for (int k = 0; k < 8; ++k) m8[k] = fmaxf(sf[k], sf[k + 8]);
#pragma unroll
    for (int w = 4; w >= 1; w >>= 1)
#pragma unroll
      for (int k = 0; k < 4; ++k)
        if (k < w) m8[k] = fmaxf(m8[k], m8[k + w]);
    float fmx = m8[0];

    // cross-half combine: viterbi (value,index) + max, one exchange round
    float ov = __shfl_xor(best, 32);
    int   oi = __shfl_xor(bpi, 32);
    float om = __shfl_xor(fmx, 32);
    bool take = (ov > best) || (ov == best && oi < bpi);
    best = take ? ov : best;
    bpi  = take ? oi : bpi;
    float m = fmaxf(fmx, om);

    // exp + pairwise sum tree
    float e[16];
#pragma unroll
    for (int i = 0; i < 16; ++i) e[i] = __expf(sf[i] - m);
    float s8[8];
#pragma unroll
    for (int k = 0; k < 8; ++k) s8[k] = e[k] + e[k + 8];
    float s4a = s8[0] + s8[4], s4b = s8[1] + s8[5];
    float s4c = s8[2] + s8[6], s4d = s8[3] + s8[7];
    float s = (s4a + s4b) + (s4c + s4d);
    s += __shfl_xor(s, 32);

    av = logit_c + best;
    af = logit_c + (m + __logf(s));

    if (h == 0) {
      bp_s[(t - 1) * CC + c] = (unsigned char)bpi;
      avs[c] = av;
      afs[c] = af;
    }
    __syncthreads();
  }

  // ---------- gold-path score (unary + binary), lane-parallel over t ----------
  float uacc = 0.0f, bacc = 0.0f;
#pragma unroll
  for (int j = 0; j < 8; ++j) {
    int t = lane + 64 * j;
    if (t < len) {
      int lt = lab[t];
      uacc += lg[t * CC + lt];
      if (t + 1 < len) {
        int ln = lab[t + 1];
        bacc += trans[lt * CC + ln];
      }
    }
  }
#pragma unroll
  for (int d = 32; d >= 1; d >>= 1) {
    uacc += __shfl_xor(uacc, d);
    bacc += __shfl_xor(bacc, d);
  }

  // ---------- last tag: argmax over c (first index on ties) ----------
  float v = av; int idx = c;
#pragma unroll
  for (int d = 1; d < 32; d <<= 1) {
    float v2 = __shfl_xor(v, d, 32);
    int   i2 = __shfl_xor(idx, d, 32);
    if (v2 > v || (v2 == v && i2 < idx)) { v = v2; idx = i2; }
  }

  // ---------- log partition ----------
  float mm = af;
#pragma unroll
  for (int d = 1; d < 32; d <<= 1) mm = fmaxf(mm, __shfl_xor(mm, d, 32));
  float ss = __expf(af - mm);
#pragma unroll
  for (int d = 1; d < 32; d <<= 1) ss += __shfl_xor(ss, d, 32);
  float log_norm = mm + __logf(ss);

  // ---------- backtrace + outputs ----------
  if (lane == 0) {
    int tag = idx;
    for (int t = len - 1; t > 0; --t) {
      out[bT + t] = (float)tag;
      tag = bp_s[(t - 1) * CC + tag];
    }
    out[bT] = (float)tag;

    float ll = uacc + bacc - log_norm;
    atomicAdd(out + (size_t)BB * TT, -ll * (1.0f / BB));
  }
  // zero-fill padded positions t >= len
  for (int t = len + lane; t < TT; t += 64) out[bT + t] = 0.0f;
}

extern "C" void kernel_launch(void* const* d_in, const int* in_sizes, int n_in,
                              void* d_out, int out_size, void* d_ws, size_t ws_size,
                              hipStream_t stream) {
  const float* logits = (const float*)d_in[0];
  const int*   seqlen = (const int*)d_in[1];
  const int*   labels = (const int*)d_in[2];
  const float* trans  = (const float*)d_in[3];
  float* out = (float*)d_out;

  zero_loss_kernel<<<1, 64, 0, stream>>>(out);
  crf_kernel<<<dim3(BB), dim3(64), 0, stream>>>(logits, seqlen, labels, trans, out);
}